// Round 5
// baseline (369.866 us; speedup 1.0000x reference)
//
#include <hip/hip_runtime.h>

// Problem constants (from reference setup_inputs)
#define B_ 64
#define C_ 256
#define T_ 2048
#define EPS_ 1e-4f
#define NPC ((float)(B_ * T_))   // elements per channel = 131072

#define T4 (T_ / 4)              // 512 vec4 per row
#define CG_ 8                    // channels per slab-half

// One-pass kernel geometry: MUST be exactly NBLK blocks (barrier target).
// 1024 blocks x 256 threads; VGPR<=85 (launch_bounds 256,6) + 17 KB LDS
// -> >=6 blocks/CU capacity = 1536 >= 1024: all blocks co-resident, spin safe.
#define NBLK 1024
#define CTILE 16
#define T4TILE 16
#define BCHUNK 32

typedef float f4 __attribute__((ext_vector_type(4)));

// ---------------------------------------------------------------------------
// One-pass fused kernel with lean device-wide barrier.
//   ws: partials [2][B_][C_] (128 KB) | bar (4 B, memset to 0 pre-launch)
// Phase A (per block): stats over 2 contiguous 64 KiB slabs (one 128 KiB
//   sequential read): b = bid>>4, channels (bid&15)*16 .. +15.
//   Publish per-(b,c) sum/ssq via agent-scope atomic stores (LLC-coherent).
// Stage gamma/beta slice into LDS (independent of partials -> before spin).
// Barrier: release atomicAdd + acquire spin on counter (1 lane/block).
// Phase C (per block): finalize 16 channels' stats from the 64 batch
//   partials (agent atomic loads), build per-thread scale/shift f4, stream
//   32 batch rows with f4 loads + nontemporal stores.
// ---------------------------------------------------------------------------
__global__ __launch_bounds__(256, 6) void bntt_onepass(const float* __restrict__ x,
                                                       const float* __restrict__ gamma,
                                                       const float* __restrict__ beta,
                                                       float* __restrict__ out,
                                                       float* __restrict__ ws) {
    float* partials   = ws;                               // [2][B_][C_]
    unsigned int* bar = (unsigned int*)(ws + 2 * B_ * C_);

    const int tid = threadIdx.x;
    const int bid = blockIdx.x;

    __shared__ float ls[CG_][256];      // also reused as sg[64][17] later
    __shared__ float lq[CG_][256];      // also reused as sb[64][17] later
    __shared__ float psum[CTILE][8], psq[CTILE][8];
    __shared__ float smean[CTILE], sistd[CTILE];

    // ---- Phase A: stats over 2 slabs (channels cbase..cbase+15 of batch b)
    const int ab    = bid >> 4;          // batch 0..63
    const int cpair = bid & 15;          // channel-pair-group 0..15
    #pragma unroll
    for (int half = 0; half < 2; ++half) {
        const int cbase = cpair * (2 * CG_) + half * CG_;
        const f4* p = (const f4*)(x + ((size_t)ab * C_ + cbase) * T_);

        float sum[CG_], ssq[CG_];
        #pragma unroll
        for (int k = 0; k < CG_; ++k) { sum[k] = 0.0f; ssq[k] = 0.0f; }
        #pragma unroll
        for (int i = 0; i < 16; ++i) {   // 4096 f4 per slab; channel = i>>1
            f4 v = p[tid + i * 256];
            const int k = i >> 1;
            sum[k] += v.x + v.y + v.z + v.w;
            ssq[k] += v.x * v.x + v.y * v.y + v.z * v.z + v.w * v.w;
        }
        #pragma unroll
        for (int k = 0; k < CG_; ++k) { ls[k][tid] = sum[k]; lq[k][tid] = ssq[k]; }
        __syncthreads();

        const int k = tid >> 5;          // channel 0..7 within slab
        const int j = tid & 31;          // lane within 32-group
        float S = 0.0f, SS = 0.0f;
        #pragma unroll
        for (int m = 0; m < 8; ++m) {
            S  += ls[k][j + m * 32];
            SS += lq[k][j + m * 32];
        }
        #pragma unroll
        for (int off = 16; off > 0; off >>= 1) {
            S  += __shfl_down(S, off);
            SS += __shfl_down(SS, off);
        }
        if (j == 0) {
            const size_t c = (size_t)cbase + k;
            __hip_atomic_store(&partials[(size_t)ab * C_ + c], S,
                               __ATOMIC_RELAXED, __HIP_MEMORY_SCOPE_AGENT);
            __hip_atomic_store(&partials[(size_t)B_ * C_ + (size_t)ab * C_ + c], SS,
                               __ATOMIC_RELAXED, __HIP_MEMORY_SCOPE_AGENT);
        }
        __syncthreads();                 // LDS reuse + order stores before release
    }
    if (tid == 0)
        __hip_atomic_fetch_add(bar, 1u, __ATOMIC_RELEASE, __HIP_MEMORY_SCOPE_AGENT);

    // ---- Phase C tile mapping
    const int tile   = bid & 511;
    const int c0     = (tile >> 5) * CTILE;      // 16 channel-tiles
    const int t4base = (tile & 31) * T4TILE;     // 32 t4-tiles
    const int b0     = (bid >> 9) * BCHUNK;

    // stage gamma/beta slice into LDS (independent of partials: hide under spin)
    float (*sg)[17] = (float (*)[17])ls;         // [64][17] <= [8][256]
    float (*sb)[17] = (float (*)[17])lq;
    {
        const int cl  = tid & 15;
        const int tl0 = tid >> 4;                // 0..15
        const int tbase = t4base * 4;
        #pragma unroll
        for (int it = 0; it < 4; ++it) {
            const int tl = tl0 + it * 16;        // 0..63
            const size_t gi = (size_t)(tbase + tl) * C_ + (c0 + cl);
            sg[tl][cl] = gamma[gi];
            sb[tl][cl] = beta[gi];
        }
    }

    // ---- lean device-wide barrier: 1 lane spins, rest park at s_barrier
    if (tid == 0) {
        while (__hip_atomic_load(bar, __ATOMIC_ACQUIRE, __HIP_MEMORY_SCOPE_AGENT)
               < (unsigned int)NBLK)
            __builtin_amdgcn_s_sleep(2);
    }
    __syncthreads();

    // ---- finalize stats: 128 threads sum 8 batches each for 16 channels
    if (tid < 128) {
        const int cl = tid & 15;
        const int h  = tid >> 4;                 // 0..7
        const size_t c = (size_t)(c0 + cl);
        float S = 0.0f, SS = 0.0f;
        #pragma unroll
        for (int m = 0; m < 8; ++m) {
            const size_t bb = (size_t)(h * 8 + m);
            S  += __hip_atomic_load(&partials[bb * C_ + c],
                                    __ATOMIC_RELAXED, __HIP_MEMORY_SCOPE_AGENT);
            SS += __hip_atomic_load(&partials[(size_t)B_ * C_ + bb * C_ + c],
                                    __ATOMIC_RELAXED, __HIP_MEMORY_SCOPE_AGENT);
        }
        psum[cl][h] = S;
        psq[cl][h]  = SS;
    }
    __syncthreads();
    if (tid < CTILE) {
        float S = 0.0f, SS = 0.0f;
        #pragma unroll
        for (int h = 0; h < 8; ++h) { S += psum[tid][h]; SS += psq[tid][h]; }
        const float mean = S / NPC;
        smean[tid] = mean;
        sistd[tid] = rsqrtf(SS / NPC - mean * mean + EPS_);
    }
    __syncthreads();

    // ---- per-thread affine + stream 32 batch rows
    const int t4i = tid & 15;
    const int ci  = tid >> 4;
    const float mean = smean[ci];
    const float istd = sistd[ci];
    f4 sc, sh;
    #pragma unroll
    for (int j = 0; j < 4; ++j) {
        const int tl = t4i * 4 + j;
        const float s1 = sg[tl][ci] * istd;
        ((float*)&sc)[j] = s1;
        ((float*)&sh)[j] = fmaf(-mean, s1, sb[tl][ci]);
    }

    size_t idx = ((size_t)b0 * C_ + (c0 + ci)) * T4 + (t4base + t4i);
    const size_t step = (size_t)C_ * T4;         // one batch row
    #pragma unroll 8
    for (int b = 0; b < BCHUNK; ++b) {
        f4 xv = ((const f4*)x)[idx];
        f4 o;
        o.x = fmaf(xv.x, sc.x, sh.x);
        o.y = fmaf(xv.y, sc.y, sh.y);
        o.z = fmaf(xv.z, sc.z, sh.z);
        o.w = fmaf(xv.w, sc.w, sh.w);
        __builtin_nontemporal_store(o, &((f4*)out)[idx]);
        idx += step;
    }
}

// ---------------------------------------------------------------------------
// Fallback (ws < 128 KB + 4): classic 2-dispatch path (R3 structure).
// ---------------------------------------------------------------------------
#define SPLITS 8
#define BPB (B_ / SPLITS)
__global__ __launch_bounds__(256) void bntt_stats_fb(const float* __restrict__ x,
                                                     float* __restrict__ partials) {
    const int c   = blockIdx.x & (C_ - 1);
    const int s   = blockIdx.x >> 8;
    const int tid = threadIdx.x;
    float sum = 0.0f, sumsq = 0.0f;
    const int b0 = s * BPB;
    #pragma unroll
    for (int b = 0; b < BPB; ++b) {
        const f4* p = (const f4*)(x + (size_t)(b0 + b) * (C_ * T_) + (size_t)c * T_);
        #pragma unroll
        for (int i = 0; i < T4 / 256; ++i) {
            f4 v = p[tid + i * 256];
            sum   += v.x + v.y + v.z + v.w;
            sumsq += v.x * v.x + v.y * v.y + v.z * v.z + v.w * v.w;
        }
    }
    #pragma unroll
    for (int off = 32; off > 0; off >>= 1) {
        sum   += __shfl_down(sum, off);
        sumsq += __shfl_down(sumsq, off);
    }
    __shared__ float ls2[4], lss2[4];
    const int wave = tid >> 6, lane = tid & 63;
    if (lane == 0) { ls2[wave] = sum; lss2[wave] = sumsq; }
    __syncthreads();
    if (tid == 0) {
        partials[s * C_ + c]               = ls2[0] + ls2[1] + ls2[2] + ls2[3];
        partials[SPLITS * C_ + s * C_ + c] = lss2[0] + lss2[1] + lss2[2] + lss2[3];
    }
}

__global__ __launch_bounds__(256) void bntt_norm_fb(const float* __restrict__ x,
                                                    const float* __restrict__ gamma,
                                                    const float* __restrict__ beta,
                                                    const float* __restrict__ partials,
                                                    float* __restrict__ out) {
    const int p   = (blockIdx.x & 511) * 256 + threadIdx.x;
    const int c   = p >> 9;
    const int t4  = p & (T4 - 1);
    const int t   = t4 * 4;
    const int b0  = (blockIdx.x >> 9) * BCHUNK;

    float S = 0.0f, SS = 0.0f;
    #pragma unroll
    for (int s = 0; s < SPLITS; ++s) {
        S  += partials[s * C_ + c];
        SS += partials[SPLITS * C_ + s * C_ + c];
    }
    const float mean = S / NPC;
    const float istd = rsqrtf(SS / NPC - mean * mean + EPS_);

    f4 sc, sh;
    #pragma unroll
    for (int j = 0; j < 4; ++j) {
        float g  = gamma[(size_t)(t + j) * C_ + c];
        float bb = beta [(size_t)(t + j) * C_ + c];
        float s1 = g * istd;
        ((float*)&sc)[j] = s1;
        ((float*)&sh)[j] = fmaf(-mean, s1, bb);
    }
    size_t idx = (size_t)(b0 * C_ + c) * T4 + t4;
    const size_t step = (size_t)C_ * T4;
    #pragma unroll 8
    for (int b = 0; b < BCHUNK; ++b) {
        f4 xv = ((const f4*)x)[idx];
        f4 o;
        o.x = fmaf(xv.x, sc.x, sh.x);
        o.y = fmaf(xv.y, sc.y, sh.y);
        o.z = fmaf(xv.z, sc.z, sh.z);
        o.w = fmaf(xv.w, sc.w, sh.w);
        __builtin_nontemporal_store(o, &((f4*)out)[idx]);
        idx += step;
    }
}

extern "C" void kernel_launch(void* const* d_in, const int* in_sizes, int n_in,
                              void* d_out, int out_size, void* d_ws, size_t ws_size,
                              hipStream_t stream) {
    const float* x     = (const float*)d_in[0];
    const float* gamma = (const float*)d_in[1];
    const float* beta  = (const float*)d_in[2];
    float* out = (float*)d_out;
    float* wsf = (float*)d_ws;

    const size_t need = (size_t)2 * B_ * C_ * sizeof(float) + sizeof(unsigned int);

    if (ws_size >= need) {
        // zero the barrier counter (graph-capturable async memset)
        hipMemsetAsync((void*)(wsf + 2 * B_ * C_), 0, sizeof(unsigned int), stream);
        bntt_onepass<<<NBLK, 256, 0, stream>>>(x, gamma, beta, out, wsf);
    } else {
        bntt_stats_fb<<<C_ * SPLITS, 256, 0, stream>>>(x, wsf);
        const int ngrid = (C_ / CTILE) * (T4 / T4TILE) * (B_ / BCHUNK);  // 1024
        bntt_norm_fb<<<ngrid, 256, 0, stream>>>(x, gamma, beta, wsf, out);
    }
}

// Round 6
// 260.705 us; speedup vs baseline: 1.4187x; 1.4187x over previous
//
#include <hip/hip_runtime.h>

// Problem constants (from reference setup_inputs)
#define B_ 64
#define C_ 256
#define T_ 2048
#define EPS_ 1e-4f
#define NPC ((float)(B_ * T_))   // elements per channel = 131072

#define T4 (T_ / 4)              // 512 vec4 per row
#define CG_ 8                    // channels per stats slab (64 KiB contiguous)

// Norm tiling: block = 4 waves; wave w owns channel c0+w, lanes own 64
// consecutive t4 -> every global access is 1 KB contiguous per wave.
#define BCHUNK 32

typedef float f4 __attribute__((ext_vector_type(4)));

// ---------------------------------------------------------------------------
// Kernel 1: slab stats. Grid = B_*(C_/CG_) = 2048 blocks of 256.
// Block (b, cg) reads ONE contiguous 64 KiB slab: channels cg*8..cg*8+7 of
// batch b. Channel-uniform accumulation acc[i>>1]; LDS transpose reduce.
//   partials layout (TRANSPOSED for coalesced finalize): [sum: [C][B]][ssq: [C][B]]
// ---------------------------------------------------------------------------
__global__ __launch_bounds__(256) void bntt_stats(const float* __restrict__ x,
                                                  float* __restrict__ partials) {
    const int bid = blockIdx.x;
    const int b   = bid >> 5;            // 64 batches
    const int cg  = bid & 31;            // 32 channel-groups of 8
    const int tid = threadIdx.x;
    const f4* p = (const f4*)(x + ((size_t)b * C_ + (size_t)cg * CG_) * T_);

    float sum[CG_], ssq[CG_];
    #pragma unroll
    for (int k = 0; k < CG_; ++k) { sum[k] = 0.0f; ssq[k] = 0.0f; }

    #pragma unroll
    for (int i = 0; i < 16; ++i) {       // slab = 4096 f4; channel = i>>1
        f4 v = p[tid + i * 256];
        const int k = i >> 1;
        sum[k] += v.x + v.y + v.z + v.w;
        ssq[k] += v.x * v.x + v.y * v.y + v.z * v.z + v.w * v.w;
    }

    __shared__ float ls[CG_][256];
    __shared__ float lq[CG_][256];
    #pragma unroll
    for (int k = 0; k < CG_; ++k) { ls[k][tid] = sum[k]; lq[k][tid] = ssq[k]; }
    __syncthreads();

    const int k = tid >> 5;              // channel 0..7 within slab
    const int j = tid & 31;              // lane within 32-group
    float S = 0.0f, SS = 0.0f;
    #pragma unroll
    for (int m = 0; m < 8; ++m) {
        S  += ls[k][j + m * 32];
        SS += lq[k][j + m * 32];
    }
    #pragma unroll
    for (int off = 16; off > 0; off >>= 1) {
        S  += __shfl_down(S, off);
        SS += __shfl_down(SS, off);
    }
    if (j == 0) {
        const size_t c = (size_t)cg * CG_ + k;
        partials[c * B_ + b]                       = S;    // [c][b]
        partials[(size_t)C_ * B_ + c * B_ + b]     = SS;
    }
}

// ---------------------------------------------------------------------------
// Kernel 2: finalize + normalize, wave-contiguous.
// Grid = 1024 blocks x 256 threads (4 waves):
//   tile = bid & 511: cq = tile>>3 -> c0 = cq*4;  tq = tile&7 -> t4base = tq*64
//   b0   = (bid>>9) * BCHUNK
// Per block:
//   - stage gamma/beta rows t in [t4base*4, +256) for channels c0..c0+3:
//     one f4 load per thread per array, scatter-transpose into sg[4][256]
//   - finalize: thread (c=tid>>6, b=tid&63) loads partials[c][b] coalesced,
//     64-lane shfl reduce -> mean/istd per channel (no extra LDS stage)
//   - wave w owns channel c0+w; lane owns t4base+lane: per-thread sc/sh f4
//     from LDS, then stream 32 batch rows. Each wave instruction touches
//     1 KB contiguous (64 lanes x 16 B) for both x load and NT store.
// ---------------------------------------------------------------------------
__global__ __launch_bounds__(256) void bntt_norm(const float* __restrict__ x,
                                                 const float* __restrict__ gamma,
                                                 const float* __restrict__ beta,
                                                 const float* __restrict__ partials,
                                                 float* __restrict__ out) {
    __shared__ float sg[4][256];         // [c_local][t_local]
    __shared__ float sb[4][256];
    __shared__ float smean[4], sistd[4];

    const int tid    = threadIdx.x;
    const int tile   = blockIdx.x & 511;
    const int c0     = (tile >> 3) * 4;          // 64 channel-quads
    const int t4base = (tile & 7) * 64;          // 8 t4-tiles of 64
    const int b0     = (blockIdx.x >> 9) * BCHUNK;

    // stage gamma/beta: thread tid handles t-row tbase+tid, 4 channels via f4
    {
        const int tbase = t4base * 4;
        const size_t gi = (size_t)(tbase + tid) * C_ + c0;   // 16B-aligned
        f4 g = *(const f4*)&gamma[gi];
        f4 bb = *(const f4*)&beta[gi];
        #pragma unroll
        for (int c = 0; c < 4; ++c) {
            sg[c][tid] = ((const float*)&g)[c];
            sb[c][tid] = ((const float*)&bb)[c];
        }
    }

    // finalize stats: thread (c, b); coalesced [c][b] loads; 64-lane reduce
    {
        const int c = tid >> 6;                  // 0..3 (== wave id)
        const int b = tid & 63;
        const size_t cc = (size_t)(c0 + c);
        float S  = partials[cc * B_ + b];
        float SS = partials[(size_t)C_ * B_ + cc * B_ + b];
        #pragma unroll
        for (int off = 32; off > 0; off >>= 1) {
            S  += __shfl_down(S, off);
            SS += __shfl_down(SS, off);
        }
        if (b == 0) {
            const float mean = S / NPC;
            smean[c] = mean;
            sistd[c] = rsqrtf(SS / NPC - mean * mean + EPS_);
        }
    }
    __syncthreads();

    // per-thread affine: wave w -> channel c0+w; lane -> t4 = t4base+lane
    const int w    = tid >> 6;
    const int lane = tid & 63;
    const float mean = smean[w];
    const float istd = sistd[w];
    f4 sc, sh;
    {
        const f4 g4 = *(const f4*)&sg[w][lane * 4];   // 16B-aligned LDS read
        const f4 b4 = *(const f4*)&sb[w][lane * 4];
        #pragma unroll
        for (int j = 0; j < 4; ++j) {
            const float s1 = ((const float*)&g4)[j] * istd;
            ((float*)&sc)[j] = s1;
            ((float*)&sh)[j] = fmaf(-mean, s1, ((const float*)&b4)[j]);
        }
    }

    // stream 32 batch rows: wave-contiguous 1 KB load + 1 KB NT store
    size_t idx = ((size_t)b0 * C_ + (c0 + w)) * T4 + (t4base + lane);
    const size_t step = (size_t)C_ * T4;         // one batch row
    #pragma unroll 8
    for (int b = 0; b < BCHUNK; ++b) {
        f4 xv = ((const f4*)x)[idx];
        f4 o;
        o.x = fmaf(xv.x, sc.x, sh.x);
        o.y = fmaf(xv.y, sc.y, sh.y);
        o.z = fmaf(xv.z, sc.z, sh.z);
        o.w = fmaf(xv.w, sc.w, sh.w);
        __builtin_nontemporal_store(o, &((f4*)out)[idx]);
        idx += step;
    }
}

// ---------------------------------------------------------------------------
// Fallback (ws < 128 KB): 8-split stats (16 KB partials) + direct norm.
// ---------------------------------------------------------------------------
#define SPLITS 8
#define BPB (B_ / SPLITS)
__global__ __launch_bounds__(256) void bntt_stats_fb(const float* __restrict__ x,
                                                     float* __restrict__ partials) {
    const int c   = blockIdx.x & (C_ - 1);
    const int s   = blockIdx.x >> 8;
    const int tid = threadIdx.x;
    float sum = 0.0f, sumsq = 0.0f;
    const int b0 = s * BPB;
    #pragma unroll
    for (int b = 0; b < BPB; ++b) {
        const f4* p = (const f4*)(x + (size_t)(b0 + b) * (C_ * T_) + (size_t)c * T_);
        #pragma unroll
        for (int i = 0; i < T4 / 256; ++i) {
            f4 v = p[tid + i * 256];
            sum   += v.x + v.y + v.z + v.w;
            sumsq += v.x * v.x + v.y * v.y + v.z * v.z + v.w * v.w;
        }
    }
    #pragma unroll
    for (int off = 32; off > 0; off >>= 1) {
        sum   += __shfl_down(sum, off);
        sumsq += __shfl_down(sumsq, off);
    }
    __shared__ float ls2[4], lss2[4];
    const int wave = tid >> 6, lane = tid & 63;
    if (lane == 0) { ls2[wave] = sum; lss2[wave] = sumsq; }
    __syncthreads();
    if (tid == 0) {
        partials[s * C_ + c]               = ls2[0] + ls2[1] + ls2[2] + ls2[3];
        partials[SPLITS * C_ + s * C_ + c] = lss2[0] + lss2[1] + lss2[2] + lss2[3];
    }
}

__global__ __launch_bounds__(256) void bntt_norm_fb(const float* __restrict__ x,
                                                    const float* __restrict__ gamma,
                                                    const float* __restrict__ beta,
                                                    const float* __restrict__ partials,
                                                    float* __restrict__ out) {
    const int p   = (blockIdx.x & 511) * 256 + threadIdx.x;
    const int c   = p >> 9;
    const int t4  = p & (T4 - 1);
    const int t   = t4 * 4;
    const int b0  = (blockIdx.x >> 9) * BCHUNK;

    float S = 0.0f, SS = 0.0f;
    #pragma unroll
    for (int s = 0; s < SPLITS; ++s) {
        S  += partials[s * C_ + c];
        SS += partials[SPLITS * C_ + s * C_ + c];
    }
    const float mean = S / NPC;
    const float istd = rsqrtf(SS / NPC - mean * mean + EPS_);

    f4 sc, sh;
    #pragma unroll
    for (int j = 0; j < 4; ++j) {
        float g  = gamma[(size_t)(t + j) * C_ + c];
        float bb = beta [(size_t)(t + j) * C_ + c];
        float s1 = g * istd;
        ((float*)&sc)[j] = s1;
        ((float*)&sh)[j] = fmaf(-mean, s1, bb);
    }
    size_t idx = (size_t)(b0 * C_ + c) * T4 + t4;
    const size_t step = (size_t)C_ * T4;
    #pragma unroll 8
    for (int b = 0; b < BCHUNK; ++b) {
        f4 xv = ((const f4*)x)[idx];
        f4 o;
        o.x = fmaf(xv.x, sc.x, sh.x);
        o.y = fmaf(xv.y, sc.y, sh.y);
        o.z = fmaf(xv.z, sc.z, sh.z);
        o.w = fmaf(xv.w, sc.w, sh.w);
        __builtin_nontemporal_store(o, &((f4*)out)[idx]);
        idx += step;
    }
}

extern "C" void kernel_launch(void* const* d_in, const int* in_sizes, int n_in,
                              void* d_out, int out_size, void* d_ws, size_t ws_size,
                              hipStream_t stream) {
    const float* x     = (const float*)d_in[0];
    const float* gamma = (const float*)d_in[1];
    const float* beta  = (const float*)d_in[2];
    float* out = (float*)d_out;
    float* partials = (float*)d_ws;

    const int ngrid = 1024;   // 512 (c,t4) tiles x 2 b-halves

    if (ws_size >= (size_t)2 * B_ * C_ * sizeof(float)) {            // 128 KB
        bntt_stats<<<B_ * (C_ / CG_), 256, 0, stream>>>(x, partials);
        bntt_norm<<<ngrid, 256, 0, stream>>>(x, gamma, beta, partials, out);
    } else {
        bntt_stats_fb<<<C_ * SPLITS, 256, 0, stream>>>(x, partials);
        bntt_norm_fb<<<ngrid, 256, 0, stream>>>(x, gamma, beta, partials, out);
    }
}